// Round 6
// baseline (155.826 us; speedup 1.0000x reference)
//
#include <hip/hip_runtime.h>
#include <math.h>
#include <utility>

#define B 4
#define CIN 8
#define COUT 16
#define OR_ 8
#define H_ 128
#define W_ 128
#define HW 16384
#define PLANE HW
#define CH_STR (OR_*HW)        // 131072
#define BATCH_STR (CIN*CH_STR) // 1048576
#define NELEM (B*BATCH_STR)    // 4194304
#define NPOS (B*OR_*HW)        // 524288
#define NB_RED 256

// fused tiling: 32x32 spatial tile per block, 8 orientations, wave = o.
// conv buffer: 40 rows x 44 dwords (11 f4) per o; dilate buffer (aliased):
// 36 rows x 44 dwords per o. Row stride 11 f4 (odd) -> b128 window reads
// spread 8 dwords/bank = conflict-free minimum.
#define TILE 32
#define CBR 40
#define STR4 11                 // f4 per row
#define CB_PL4 (CBR*STR4)       // 440 f4 per o-plane (conv)
#define DBR 36
#define DB_PL4 (DBR*STR4)       // 396 f4 per o-plane (dilate)

typedef __attribute__((ext_vector_type(4))) float f4;

// ---------------- compile-time tap geometry ----------------
__host__ __device__ constexpr double m_cos(int o) {
  const double r = 0.70710678118654752440;
  const double t[8] = {1.0, r, 0.0, -r, -1.0, -r, 0.0, r};
  return t[o];
}
__host__ __device__ constexpr double m_sin(int o) {
  const double r = 0.70710678118654752440;
  const double t[8] = {0.0, r, 1.0, r, 0.0, -r, -1.0, -r};
  return t[o];
}
// j = (qy+1)*3 + (qx+1)
__host__ __device__ constexpr double tap_dx(int o, int j) {
  return m_cos(o)*(j % 3 - 1) - m_sin(o)*(j / 3 - 1);
}
__host__ __device__ constexpr double tap_dy(int o, int j) {
  return m_sin(o)*(j % 3 - 1) + m_cos(o)*(j / 3 - 1);
}
__host__ __device__ constexpr int ifloor(double v) {
  int i = (int)v;
  return ((double)i > v) ? i - 1 : i;
}
__host__ __device__ constexpr int tap_ix(int o, int j) { return ifloor(tap_dx(o, j)); } // [-2,1]
__host__ __device__ constexpr int tap_iy(int o, int j) { return ifloor(tap_dy(o, j)); }
__host__ __device__ constexpr float tap_fx(int o, int j) { return (float)(tap_dx(o, j) - tap_ix(o, j)); }
__host__ __device__ constexpr float tap_fy(int o, int j) { return (float)(tap_dy(o, j) - tap_iy(o, j)); }
__host__ __device__ constexpr float corner_w(int o, int j, int dyb, int dxb) {
  float fy = tap_fy(o, j), fx = tap_fx(o, j);
  return (dyb ? fy : 1.0f - fy) * (dxb ? fx : 1.0f - fx);
}
// window row (0..7) for output row rr (0..3) of a 4x4 patch
__host__ __device__ constexpr int wrow(int o, int j, int rr, int dyb) {
  return rr + tap_iy(o, j) + dyb + 2;
}
// window col (0..7) for output col i (0..3)
__host__ __device__ constexpr int wcol(int o, int j, int i, int dxb) {
  return i + tap_ix(o, j) + dxb + 2;
}
__host__ __device__ constexpr bool wrow_used(int o, int wr) {
  for (int j = 0; j < 9; ++j)
    for (int rr = 0; rr < 4; ++rr)
      for (int dyb = 0; dyb < 2; ++dyb)
        for (int dxb = 0; dxb < 2; ++dxb)
          if (corner_w(o, j, dyb, dxb) != 0.0f && wrow(o, j, rr, dyb) == wr)
            return true;
  return false;
}

template<int N> struct Rep {
  template<class F> __device__ __forceinline__ static void run(F&& f) {
    Rep<N-1>::run(f);
    f(std::integral_constant<int, N-1>{});
  }
};
template<> struct Rep<0> {
  template<class F> __device__ __forceinline__ static void run(F&&) {}
};

// 4x4-output morph patch. sm = LDS base (f4), PLF4 = f4 per o-plane,
// rbase = window row base (window rows rbase..rbase+7), pcc = f4 col index.
template<int O, int DIL, int PLF4>
__device__ __forceinline__ void morph_patch(const f4* __restrict__ sm,
                                            const float* __restrict__ kL,
                                            int rbase, int pcc, float acc[16]) {
  Rep<3>::run([&](auto qc) {
    constexpr int qti = decltype(qc)::value;
    const f4* p = sm + ((O + qti + 7) & 7) * PLF4 + rbase * STR4 + pcc;
    float kq[9];
    #pragma unroll
    for (int jj = 0; jj < 9; ++jj) kq[jj] = kL[qti*9 + jj];
    f4 wv[8][2];
    Rep<8>::run([&](auto wrc) {
      constexpr int wr = decltype(wrc)::value;
      if constexpr (wrow_used(O, wr)) {
        wv[wr][0] = p[wr*STR4];
        wv[wr][1] = p[wr*STR4 + 1];
      }
    });
    Rep<9>::run([&](auto jc) {
      constexpr int j = decltype(jc)::value;
      float kk = kq[j];
      float base = DIL ? -kk : kk;
      Rep<16>::run([&](auto oc) {
        constexpr int rr = decltype(oc)::value >> 2;
        constexpr int i  = decltype(oc)::value & 3;
        float v = base;
        Rep<4>::run([&](auto cc2) {
          constexpr int dyb = decltype(cc2)::value >> 1, dxb = decltype(cc2)::value & 1;
          constexpr float Wgt = corner_w(O, j, dyb, dxb);
          if constexpr (Wgt != 0.0f) {
            constexpr int WR = wrow(O, j, rr, dyb);
            constexpr int WC = wcol(O, j, i, dxb);
            v = fmaf(Wgt, wv[WR][WC >> 2][WC & 3], v);
          }
        });
        acc[rr*4+i] = DIL ? fmaxf(acc[rr*4+i], v) : fminf(acc[rr*4+i], v);
      });
    });
  });
}

template<int O>
__device__ __forceinline__ void dil_compute(const f4* __restrict__ sm,
                                            const float* __restrict__ kL, int lane,
                                            float accA[16], float accB[16]) {
  int prA = lane / 9, pcA = lane - prA*9;             // patch A: always valid (64 < 81)
  morph_patch<O, 1, CB_PL4>(sm, kL, prA*4, pcA, accA);
  int pB = lane + 64;
  if (pB < 81) {
    int prB = pB / 9, pcB = pB - prB*9;
    morph_patch<O, 1, CB_PL4>(sm, kL, prB*4, pcB, accB);
  }
}

template<int O>
__device__ __forceinline__ void ero_compute(const f4* __restrict__ sm,
                                            const float* __restrict__ kL, int lane,
                                            float* __restrict__ dst) {
  int pr = lane >> 3, pc = lane & 7;
  float acc[16];
  #pragma unroll
  for (int i = 0; i < 16; ++i) acc[i] = INFINITY;
  morph_patch<O, 0, DB_PL4>(sm, kL, pr*4, pc, acc);
  #pragma unroll
  for (int rr = 0; rr < 4; ++rr) {
    f4 v = {acc[rr*4+0], acc[rr*4+1], acc[rr*4+2], acc[rr*4+3]};
    *(f4*)(dst + (pr*4+rr)*W_ + pc*4) = v;
  }
}

// conv -> dilate -> erode, one (b,c,32x32 tile) per block, 512 threads.
__global__ __launch_bounds__(512, 4)
void fused_kernel(const float* __restrict__ x,
                  const float* __restrict__ g0,
                  const float* __restrict__ mdil,
                  const float* __restrict__ mero,
                  float* __restrict__ u3) {
  __shared__ f4 smem[8*CB_PL4];          // 3520 f4 = 56.3 KB (dilbuf aliases)
  __shared__ float kdilL[27], keroL[27];
  __shared__ float cw00[8], cw01[8], cw10[8], cw11[8], ccf[1];
  __shared__ int   cply1[8], cply2[8], ciy0[8], cix0[8];

  int blk = blockIdx.x;
  int tx = blk & 3, ty = (blk >> 2) & 3, c = (blk >> 4) & 7, b = blk >> 7;
  int h0 = ty*TILE, w0 = tx*TILE;
  int t = threadIdx.x;
  int wid = t >> 6, lane = t & 63;

  // ---- stage 0: per-block tables (this block's channel c only) ----
  {
    const double TWO_PI = 6.283185307179586476925286766559;
    if (t < 54) {
      const double P  = 2.0*0.65/(2.0*0.65 - 1.0);
      const double NU = (2.0*0.65 - 1.0)*pow(2.0*0.65, -P);
      int which = t / 27;
      int j = t % 27;                // j = (qt+1)*9 + (qy+1)*3 + (qx+1)
      int qt = j/9 - 1;
      int qy = (j/3)%3 - 1;
      int qx = j%3 - 1;
      double dth = qt * (TWO_PI/OR_);
      double c1, c2, c3;
      if (qt == 0) { c1 = qx; c2 = qy; c3 = 0.0; }
      else {
        double h = 0.5*dth;
        double cot = cos(h)/sin(h);
        c1 = h*(qx*cot + qy);
        c2 = h*(-qx + qy*cot);
        c3 = dth;
      }
      const float* m = which ? mero : mdil;
      double a0 = (double)m[c*3+0]*c1;
      double a1 = (double)m[c*3+1]*c2;
      double a2 = (double)m[c*3+2]*c3;
      double s = a0*a0 + a1*a1 + a2*a2;
      float k = (float)(NU * pow(s, P*0.5));
      (which ? keroL : kdilL)[j] = k;
    } else if (t >= 64 && t < 72) {
      int o = t - 64;
      float x0 = g0[c*3+0], y0 = g0[c*3+1], th0 = g0[c*3+2];
      float a = (float)(o*(TWO_PI/OR_)) - th0;
      float ca = cosf(a), sa = sinf(a);
      float dxv = -(ca*x0 - sa*y0);
      float dyv = -(sa*x0 + ca*y0);
      float fy0 = floorf(dyv), fx0 = floorf(dxv);
      float fy = dyv - fy0, fx = dxv - fx0;
      ciy0[o] = (int)fy0;
      cix0[o] = (int)fx0;
      cw00[o] = (1.f-fy)*(1.f-fx);
      cw01[o] = (1.f-fy)*fx;
      cw10[o] = fy*(1.f-fx);
      cw11[o] = fy*fx;
      float tt = th0 * (float)(OR_/TWO_PI);
      float fi = floorf(tt);
      int ci = (int)fi;
      cply1[o] = (o - ci) & 7;
      cply2[o] = (o - ci - 1) & 7;
      if (o == 0) ccf[0] = tt - fi;
    }
  }
  __syncthreads();

  // ---- stage 1: convection into convbuf (wave wid handles o = wid) ----
  {
    const int o = wid;
    const float* p1 = x + b*BATCH_STR + c*CH_STR + cply1[o]*PLANE;
    const float* p2 = x + b*BATCH_STR + c*CH_STR + cply2[o]*PLANE;
    const int iy0 = ciy0[o], ix0 = cix0[o];
    const float w00 = cw00[o], w01 = cw01[o], w10 = cw10[o], w11 = cw11[o];
    const float cfv = ccf[0];
    float* cbf = (float*)(smem + o*CB_PL4);
    #pragma unroll
    for (int it = 0; it < 7; ++it) {
      int q = lane + it*64;
      if (q < 400) {                     // 40 rows x 10 col-quads
        int r = q / 10, cq = q - r*10;
        int gr = h0 - 4 + r;
        int gc4 = w0 - 4 + cq*4;
        int iy = gr + iy0, ix = gc4 + ix0;
        bool ok = (gr >= 0) & (gr <= 127) & (gc4 >= 0) & (gc4+3 <= 127)
                & (iy >= 0) & (iy <= 126) & (ix >= 0) & (ix+4 <= 127);
        if (ok) {
          const float* q1 = p1 + iy*W_ + ix;
          const float* q2 = p2 + iy*W_ + ix;
          float a[5], bb[5], cc[5], dd[5];
          #pragma unroll
          for (int k = 0; k < 5; ++k) {
            a[k] = q1[k]; bb[k] = q1[W_+k]; cc[k] = q2[k]; dd[k] = q2[W_+k];
          }
          f4 res;
          #pragma unroll
          for (int i = 0; i < 4; ++i) {
            float v1 = w00*a[i] + w01*a[i+1] + w10*bb[i] + w11*bb[i+1];
            float v2 = w00*cc[i] + w01*cc[i+1] + w10*dd[i] + w11*dd[i+1];
            res[i] = (1.0f - cfv)*v1 + cfv*v2;
          }
          *(f4*)(cbf + r*44 + cq*4) = res;
        } else {
          int gh = min(max(gr, 0), 127);
          #pragma unroll
          for (int i = 0; i < 4; ++i) {
            int gw = min(max(gc4 + i, 0), 127);
            int yy = gh + iy0, xx = gw + ix0;
            int r0 = min(max(yy, 0), 127), r1 = min(max(yy+1, 0), 127);
            int c0 = min(max(xx, 0), 127), c1 = min(max(xx+1, 0), 127);
            float v1 = w00*p1[r0*W_+c0] + w01*p1[r0*W_+c1] + w10*p1[r1*W_+c0] + w11*p1[r1*W_+c1];
            float v2 = w00*p2[r0*W_+c0] + w01*p2[r0*W_+c1] + w10*p2[r1*W_+c0] + w11*p2[r1*W_+c1];
            cbf[r*44 + cq*4 + i] = (1.0f - cfv)*v1 + cfv*v2;
          }
        }
      }
    }
  }
  __syncthreads();

  // ---- stage 2: dilate (results held in registers; dilbuf aliases convbuf) ----
  float accA[16], accB[16];
  #pragma unroll
  for (int i = 0; i < 16; ++i) { accA[i] = -INFINITY; accB[i] = -INFINITY; }
  switch (wid) {
    case 0: dil_compute<0>(smem, kdilL, lane, accA, accB); break;
    case 1: dil_compute<1>(smem, kdilL, lane, accA, accB); break;
    case 2: dil_compute<2>(smem, kdilL, lane, accA, accB); break;
    case 3: dil_compute<3>(smem, kdilL, lane, accA, accB); break;
    case 4: dil_compute<4>(smem, kdilL, lane, accA, accB); break;
    case 5: dil_compute<5>(smem, kdilL, lane, accA, accB); break;
    case 6: dil_compute<6>(smem, kdilL, lane, accA, accB); break;
    default: dil_compute<7>(smem, kdilL, lane, accA, accB); break;
  }
  __syncthreads();
  // store dilate results into dilbuf (aliased region)
  {
    f4* db = smem + wid*DB_PL4;
    int pr = lane / 9, pc = lane - pr*9;
    f4* d = db + pr*4*STR4 + pc;
    #pragma unroll
    for (int rr = 0; rr < 4; ++rr) {
      f4 v = {accA[rr*4+0], accA[rr*4+1], accA[rr*4+2], accA[rr*4+3]};
      d[rr*STR4] = v;
    }
    if (lane < 17) {
      int p = lane + 64;
      int pr2 = p / 9, pc2 = p - pr2*9;
      f4* d2 = db + pr2*4*STR4 + pc2;
      #pragma unroll
      for (int rr = 0; rr < 4; ++rr) {
        f4 v = {accB[rr*4+0], accB[rr*4+1], accB[rr*4+2], accB[rr*4+3]};
        d2[rr*STR4] = v;
      }
    }
  }
  __syncthreads();

  // ---- stage 2b: replicate dilbuf halo for edge tiles (clamped semantics) ----
  if ((h0 == 0) | (h0 == 96) | (w0 == 0) | (w0 == 96)) {
    float* df = (float*)smem;
    #pragma unroll
    for (int k2 = 0; k2 < 5; ++k2) {
      int i = t + k2*512;
      if (i < 2176) {                    // 8 o x 272 halo cells
        int o = i / 272, rest = i - o*272;
        int row, col;
        if (rest < 144) {
          int rr2 = rest / 36;
          col = rest - rr2*36;
          row = (rr2 < 2) ? rr2 : rr2 + 32;      // rows 0,1,34,35 full width
        } else {
          int j2 = rest - 144;
          col = j2 & 3; col = (col < 2) ? col : col + 32;  // cols 0,1,34,35
          row = 2 + (j2 >> 2);                   // rows 2..33
        }
        int vh = h0 - 2 + row, vw = w0 - 2 + col;
        int dr = min(max(vh, 0), 127) - vh;
        int dc = min(max(vw, 0), 127) - vw;
        if ((dr | dc) != 0) {
          df[(o*DBR + row)*44 + col] = df[(o*DBR + row + dr)*44 + col + dc];
        }
      }
    }
  }
  __syncthreads();

  // ---- stage 3: erode -> u3 ----
  {
    float* dst = u3 + ((b*CIN + c)*OR_ + wid)*PLANE + h0*W_ + w0;
    switch (wid) {
      case 0: ero_compute<0>(smem, keroL, lane, dst); break;
      case 1: ero_compute<1>(smem, keroL, lane, dst); break;
      case 2: ero_compute<2>(smem, keroL, lane, dst); break;
      case 3: ero_compute<3>(smem, keroL, lane, dst); break;
      case 4: ero_compute<4>(smem, keroL, lane, dst); break;
      case 5: ero_compute<5>(smem, keroL, lane, dst); break;
      case 6: ero_compute<6>(smem, keroL, lane, dst); break;
      default: ero_compute<7>(smem, keroL, lane, dst); break;
    }
  }
}

__global__ void gram_kernel(const float* __restrict__ u, double* __restrict__ part) {
  int t8 = blockIdx.x*256 + threadIdx.x;     // NPOS/8 = 65536 threads
  int hw = (t8 & 2047) << 3;
  int o  = (t8 >> 11) & 7;
  int b  = t8 >> 14;
  const float* base = u + b*BATCH_STR + o*PLANE + hw;
  f4 v0[8], v1[8];
  #pragma unroll
  for (int c = 0; c < 8; c++) {
    v0[c] = *(const f4*)(base + c*CH_STR);
    v1[c] = *(const f4*)(base + c*CH_STR + 4);
  }
  float S[8], G[36];
  #pragma unroll
  for (int c = 0; c < 8; c++)
    S[c] = (v0[c].x + v0[c].y) + (v0[c].z + v0[c].w)
         + (v1[c].x + v1[c].y) + (v1[c].z + v1[c].w);
  {
    int t = 0;
    #pragma unroll
    for (int c = 0; c < 8; c++)
      #pragma unroll
      for (int c2 = c; c2 < 8; c2++) {
        G[t] = v0[c].x*v0[c2].x + v0[c].y*v0[c2].y + v0[c].z*v0[c2].z + v0[c].w*v0[c2].w
             + v1[c].x*v1[c2].x + v1[c].y*v1[c2].y + v1[c].z*v1[c2].z + v1[c].w*v1[c2].w;
        t++;
      }
  }
  __shared__ double lds[4][44];
  int lane = threadIdx.x & 63;
  int wave = threadIdx.x >> 6;
  for (int t = 0; t < 44; t++) {
    double vv = (double)((t < 8) ? S[t] : G[t-8]);
    for (int off = 32; off; off >>= 1) vv += __shfl_down(vv, off);
    if (lane == 0) lds[wave][t] = vv;
  }
  __syncthreads();
  if (threadIdx.x < 44) {
    part[blockIdx.x*44 + threadIdx.x] =
      lds[0][threadIdx.x] + lds[1][threadIdx.x] + lds[2][threadIdx.x] + lds[3][threadIdx.x];
  }
}

__global__ void stats_kernel(const double* __restrict__ part, const float* __restrict__ weight,
                             const float* __restrict__ gamma, const float* __restrict__ beta,
                             float* __restrict__ ss) {
  __shared__ double tot[44];
  int t = threadIdx.x;
  if (t < 352) {
    int cnt = t >> 3, j = t & 7;
    double s = 0.0;
    #pragma unroll 8
    for (int k = 0; k < 32; ++k) s += part[(j + (k << 3))*44 + cnt];
    s += __shfl_down(s, 4);
    s += __shfl_down(s, 2);
    s += __shfl_down(s, 1);
    if (j == 0) tot[cnt] = s;
  }
  __syncthreads();
  if (t < 16) {
    double m = 0.0;
    for (int c = 0; c < 8; c++) m += (double)weight[c*COUT + t] * tot[c];
    double e2 = 0.0;
    int idx = 8;
    for (int c = 0; c < 8; c++)
      for (int c2 = c; c2 < 8; c2++) {
        double wp = (double)weight[c*COUT + t] * (double)weight[c2*COUT + t];
        e2 += (c2 == c ? 1.0 : 2.0) * wp * tot[idx];
        idx++;
      }
    double N = (double)NPOS;
    m /= N; e2 /= N;
    double var = e2 - m*m;
    double inv = rsqrt(var + 1e-5);
    float sc = (float)(inv * (double)gamma[t]);
    ss[t]      = sc;
    ss[16 + t] = beta[t] - (float)m * sc;
  }
}

__global__ void final_kernel(const float* __restrict__ u, const float* __restrict__ weight,
                             const float* __restrict__ ss, float* __restrict__ out) {
  __shared__ float Wsh[8][16];
  __shared__ float scale[16], shift[16];
  int t = threadIdx.x;
  if (t < 128) Wsh[t >> 4][t & 15] = weight[t];
  if (t < 16) { scale[t] = ss[t]; shift[t] = ss[16 + t]; }
  __syncthreads();
  int t4 = blockIdx.x*256 + threadIdx.x;     // 131072 threads
  int hw = (t4 & 4095) << 2;
  int o  = (t4 >> 12) & 7;
  int b  = t4 >> 15;
  const float* base = u + b*BATCH_STR + o*PLANE + hw;
  f4 v[8];
  #pragma unroll
  for (int c = 0; c < 8; c++) v[c] = *(const f4*)(base + c*CH_STR);
  float* ob = out + b*(COUT*CH_STR) + o*PLANE + hw;
  #pragma unroll
  for (int d = 0; d < 16; d++) {
    f4 y = {0.f, 0.f, 0.f, 0.f};
    #pragma unroll
    for (int c = 0; c < 8; c++) {
      float wv = Wsh[c][d];
      y.x = fmaf(v[c].x, wv, y.x);
      y.y = fmaf(v[c].y, wv, y.y);
      y.z = fmaf(v[c].z, wv, y.z);
      y.w = fmaf(v[c].w, wv, y.w);
    }
    float sc = scale[d], sh = shift[d];
    f4 r = { fmaf(y.x, sc, sh), fmaf(y.y, sc, sh), fmaf(y.z, sc, sh), fmaf(y.w, sc, sh) };
    *(f4*)(ob + d*CH_STR) = r;
  }
}

extern "C" void kernel_launch(void* const* d_in, const int* in_sizes, int n_in,
                              void* d_out, int out_size, void* d_ws, size_t ws_size,
                              hipStream_t stream) {
  const float* x      = (const float*)d_in[0];
  const float* g0     = (const float*)d_in[1];
  const float* mdil   = (const float*)d_in[2];
  const float* mero   = (const float*)d_in[3];
  const float* weight = (const float*)d_in[4];
  const float* gamma  = (const float*)d_in[5];
  const float* beta   = (const float*)d_in[6];
  float* out = (float*)d_out;

  char* ws = (char*)d_ws;
  float*  ss   = (float*)(ws + 8*1024);               // 32 floats
  double* part = (double*)(ws + 16*1024);             // 256*44*8 = 90 KB
  float*  u3   = (float*)(ws + (size_t)1*1024*1024);  // linear, 16 MB

  fused_kernel<<<B*CIN*16, 512, 0, stream>>>(x, g0, mdil, mero, u3);
  gram_kernel<<<NB_RED, 256, 0, stream>>>(u3, part);
  stats_kernel<<<1, 384, 0, stream>>>(part, weight, gamma, beta, ss);
  final_kernel<<<NPOS/4/256, 256, 0, stream>>>(u3, weight, ss, out);
}

// Round 7
// 125.321 us; speedup vs baseline: 1.2434x; 1.2434x over previous
//
#include <hip/hip_runtime.h>
#include <math.h>
#include <utility>

#define B 4
#define CIN 8
#define COUT 16
#define OR_ 8
#define H_ 128
#define W_ 128
#define HW 16384
#define PLANE HW
#define CH_STR (OR_*HW)        // 131072
#define BATCH_STR (CIN*CH_STR) // 1048576
#define NELEM (B*BATCH_STR)    // 4194304
#define NPOS (B*OR_*HW)        // 524288
#define NB_RED 256

// fused tiling: 16x16 tile per block, 8 waves, wave = orientation.
// LDS rows are 44 dwords (11 f4, odd f4-stride) -> b128 window reads spread
// across all 8 bank-phases. Dilate buffer ALIASES conv buffer (dilate results
// held in registers across a barrier) to keep LDS at 34 KB -> 4 blocks/CU.
#define TILE 16
#define CBR 24                 // conv rows (tile + 2*4 halo)
#define DBR 20                 // dilate rows (tile + 2*2 halo)
#define STR4 11                // f4 per row
#define CB_PL4 (CBR*STR4)      // 264 f4 per o-plane (conv)
#define DB_PL4 (DBR*STR4)      // 220 f4 per o-plane (dilate, aliased)

typedef __attribute__((ext_vector_type(4))) float f4;

// ---------------- compile-time tap geometry ----------------
__host__ __device__ constexpr double m_cos(int o) {
  const double r = 0.70710678118654752440;
  const double t[8] = {1.0, r, 0.0, -r, -1.0, -r, 0.0, r};
  return t[o];
}
__host__ __device__ constexpr double m_sin(int o) {
  const double r = 0.70710678118654752440;
  const double t[8] = {0.0, r, 1.0, r, 0.0, -r, -1.0, -r};
  return t[o];
}
// j = (qy+1)*3 + (qx+1)
__host__ __device__ constexpr double tap_dx(int o, int j) {
  return m_cos(o)*(j % 3 - 1) - m_sin(o)*(j / 3 - 1);
}
__host__ __device__ constexpr double tap_dy(int o, int j) {
  return m_sin(o)*(j % 3 - 1) + m_cos(o)*(j / 3 - 1);
}
__host__ __device__ constexpr int ifloor(double v) {
  int i = (int)v;
  return ((double)i > v) ? i - 1 : i;
}
__host__ __device__ constexpr int tap_ix(int o, int j) { return ifloor(tap_dx(o, j)); } // [-2,1]
__host__ __device__ constexpr int tap_iy(int o, int j) { return ifloor(tap_dy(o, j)); }
__host__ __device__ constexpr float tap_fx(int o, int j) { return (float)(tap_dx(o, j) - tap_ix(o, j)); }
__host__ __device__ constexpr float tap_fy(int o, int j) { return (float)(tap_dy(o, j) - tap_iy(o, j)); }
__host__ __device__ constexpr float corner_w(int o, int j, int dyb, int dxb) {
  float fy = tap_fy(o, j), fx = tap_fx(o, j);
  return (dyb ? fy : 1.0f - fy) * (dxb ? fx : 1.0f - fx);
}
__host__ __device__ constexpr int corner_r(int o, int j, int dyb) { return tap_iy(o, j) + dyb + 2; }            // 0..4
__host__ __device__ constexpr int corner_c(int o, int j, int i, int dxb) { return i + tap_ix(o, j) + dxb + 2; } // 0..7
__host__ __device__ constexpr bool row_used(int o, int r) {
  for (int j = 0; j < 9; ++j)
    for (int dyb = 0; dyb < 2; ++dyb)
      for (int dxb = 0; dxb < 2; ++dxb)
        if (corner_w(o, j, dyb, dxb) != 0.0f && corner_r(o, j, dyb) == r)
          return true;
  return false;
}

template<int N> struct Rep {
  template<class F> __device__ __forceinline__ static void run(F&& f) {
    Rep<N-1>::run(f);
    f(std::integral_constant<int, N-1>{});
  }
};
template<> struct Rep<0> {
  template<class F> __device__ __forceinline__ static void run(F&&) {}
};

// 4-px (one row) morph group. sm = LDS base in f4 units; window = 5 rows x
// 8 cols read as 2x ds_read_b128 per used row. row = window row base, gc4 =
// window f4 col base.
template<int O, int DIL, int PLF4>
__device__ __forceinline__ void morph_tile_lds(const f4* __restrict__ sm,
                                               const float* __restrict__ kt,
                                               int row, int gc4, float acc[4]) {
  Rep<3>::run([&](auto qc) {
    constexpr int qti = decltype(qc)::value;
    const f4* p = sm + ((O + qti + 7) & 7) * PLF4 + row * STR4 + gc4;
    f4 wv[5][2];
    Rep<5>::run([&](auto rc) {
      constexpr int r = decltype(rc)::value;
      if constexpr (row_used(O, r)) {
        wv[r][0] = p[r*STR4];
        wv[r][1] = p[r*STR4 + 1];
      }
    });
    Rep<9>::run([&](auto jc) {
      constexpr int j = decltype(jc)::value;
      float k = kt[qti*9 + j];
      float base = DIL ? -k : k;
      Rep<4>::run([&](auto ic) {
        constexpr int i = decltype(ic)::value;
        float v = base;
        Rep<4>::run([&](auto cc2) {
          constexpr int dyb = decltype(cc2)::value >> 1, dxb = decltype(cc2)::value & 1;
          constexpr float Wgt = corner_w(O, j, dyb, dxb);
          if constexpr (Wgt != 0.0f) {
            constexpr int R = corner_r(O, j, dyb);
            constexpr int C = corner_c(O, j, i, dxb);
            v = fmaf(Wgt, wv[R][C >> 2][C & 3], v);
          }
        });
        acc[i] = DIL ? fmaxf(acc[i], v) : fminf(acc[i], v);
      });
    });
  });
}

template<int O>
__device__ __forceinline__ void dil_compute(const f4* __restrict__ sm,
                                            const float* __restrict__ kt, int lane,
                                            float accA[4], float accB[4]) {
  int rA = lane / 5, cA = lane - rA*5;        // groups 0..63
  morph_tile_lds<O, 1, CB_PL4>(sm, kt, rA, cA, accA);
  if (lane < 36) {                            // groups 64..99
    int g = lane + 64;
    int rB = g / 5, cB = g - rB*5;
    morph_tile_lds<O, 1, CB_PL4>(sm, kt, rB, cB, accB);
  }
}

template<int O>
__device__ __forceinline__ void ero_compute(const f4* __restrict__ sm,
                                            const float* __restrict__ kt, int lane,
                                            float* __restrict__ dst) {
  int pr = lane >> 2, pc = lane & 3;          // 16 rows x 4 col-quads
  float acc[4] = {INFINITY, INFINITY, INFINITY, INFINITY};
  morph_tile_lds<O, 0, DB_PL4>(sm, kt, pr, pc, acc);
  f4 v = {acc[0], acc[1], acc[2], acc[3]};
  *(f4*)(dst + pr*W_ + pc*4) = v;
}

// conv -> dilate -> erode, one (b,c,16x16 tile) per block, 512 threads.
__global__ __launch_bounds__(512, 4)
void fused_kernel(const float* __restrict__ x,
                  const float* __restrict__ g0,
                  const float* __restrict__ mdil,
                  const float* __restrict__ mero,
                  float* __restrict__ u3) {
  __shared__ f4 smem[8*CB_PL4];          // 2112 f4 = 33.8 KB (dilbuf aliases)
  __shared__ float kdilL[27], keroL[27];
  __shared__ float cw00[8], cw01[8], cw10[8], cw11[8], ccf[1];
  __shared__ int   cply1[8], cply2[8], ciy0[8], cix0[8];

  int blk = blockIdx.x;
  int tx = blk & 7, ty = (blk >> 3) & 7, c = (blk >> 6) & 7, b = blk >> 9;
  int h0 = ty*TILE, w0 = tx*TILE;
  int t = threadIdx.x;
  int wid = t >> 6, lane = t & 63;

  // ---- stage 0: per-block tables (channel c only) ----
  {
    const double TWO_PI = 6.283185307179586476925286766559;
    if (t < 54) {
      const double P  = 2.0*0.65/(2.0*0.65 - 1.0);
      const double NU = (2.0*0.65 - 1.0)*pow(2.0*0.65, -P);
      int which = t / 27;
      int j = t % 27;                // j = (qt+1)*9 + (qy+1)*3 + (qx+1)
      int qt = j/9 - 1;
      int qy = (j/3)%3 - 1;
      int qx = j%3 - 1;
      double dth = qt * (TWO_PI/OR_);
      double c1, c2, c3;
      if (qt == 0) { c1 = qx; c2 = qy; c3 = 0.0; }
      else {
        double h = 0.5*dth;
        double cot = cos(h)/sin(h);
        c1 = h*(qx*cot + qy);
        c2 = h*(-qx + qy*cot);
        c3 = dth;
      }
      const float* m = which ? mero : mdil;
      double a0 = (double)m[c*3+0]*c1;
      double a1 = (double)m[c*3+1]*c2;
      double a2 = (double)m[c*3+2]*c3;
      double s = a0*a0 + a1*a1 + a2*a2;
      float k = (float)(NU * pow(s, P*0.5));
      (which ? keroL : kdilL)[j] = k;
    } else if (t >= 64 && t < 72) {
      int o = t - 64;
      float x0 = g0[c*3+0], y0 = g0[c*3+1], th0 = g0[c*3+2];
      float a = (float)(o*(TWO_PI/OR_)) - th0;
      float ca = cosf(a), sa = sinf(a);
      float dxv = -(ca*x0 - sa*y0);
      float dyv = -(sa*x0 + ca*y0);
      float fy0 = floorf(dyv), fx0 = floorf(dxv);
      float fy = dyv - fy0, fx = dxv - fx0;
      ciy0[o] = (int)fy0;
      cix0[o] = (int)fx0;
      cw00[o] = (1.f-fy)*(1.f-fx);
      cw01[o] = (1.f-fy)*fx;
      cw10[o] = fy*(1.f-fx);
      cw11[o] = fy*fx;
      float tt = th0 * (float)(OR_/TWO_PI);
      float fi = floorf(tt);
      int ci = (int)fi;
      cply1[o] = (o - ci) & 7;
      cply2[o] = (o - ci - 1) & 7;
      if (o == 0) ccf[0] = tt - fi;
    }
  }
  __syncthreads();

  // ---- stage 1: convection into convbuf (wave wid handles o = wid) ----
  {
    const int o = wid;
    const float* p1 = x + b*BATCH_STR + c*CH_STR + cply1[o]*PLANE;
    const float* p2 = x + b*BATCH_STR + c*CH_STR + cply2[o]*PLANE;
    const int iy0 = ciy0[o], ix0 = cix0[o];
    const float w00 = cw00[o], w01 = cw01[o], w10 = cw10[o], w11 = cw11[o];
    const float cfv = ccf[0];
    float* cbf = (float*)(smem + o*CB_PL4);
    #pragma unroll
    for (int it = 0; it < 3; ++it) {
      int q = lane + it*64;
      if (q < 144) {                     // 24 rows x 6 col-quads
        int r = q / 6, cq = q - r*6;
        int gr = h0 - 4 + r;
        int gc4 = w0 - 4 + cq*4;
        int iy = gr + iy0, ix = gc4 + ix0;
        bool ok = (gr >= 0) & (gr <= 127) & (gc4 >= 0) & (gc4+3 <= 127)
                & (iy >= 0) & (iy <= 126) & (ix >= 0) & (ix+4 <= 127);
        if (ok) {
          const float* q1 = p1 + iy*W_ + ix;
          const float* q2 = p2 + iy*W_ + ix;
          float a[5], bb[5], cc[5], dd[5];
          #pragma unroll
          for (int k = 0; k < 5; ++k) {
            a[k] = q1[k]; bb[k] = q1[W_+k]; cc[k] = q2[k]; dd[k] = q2[W_+k];
          }
          f4 res;
          #pragma unroll
          for (int i = 0; i < 4; ++i) {
            float v1 = w00*a[i] + w01*a[i+1] + w10*bb[i] + w11*bb[i+1];
            float v2 = w00*cc[i] + w01*cc[i+1] + w10*dd[i] + w11*dd[i+1];
            res[i] = (1.0f - cfv)*v1 + cfv*v2;
          }
          *(f4*)(cbf + r*44 + cq*4) = res;
        } else {
          int gh = min(max(gr, 0), 127);
          #pragma unroll
          for (int i = 0; i < 4; ++i) {
            int gw = min(max(gc4 + i, 0), 127);
            int yy = gh + iy0, xx = gw + ix0;
            int r0 = min(max(yy, 0), 127), r1 = min(max(yy+1, 0), 127);
            int c0 = min(max(xx, 0), 127), c1 = min(max(xx+1, 0), 127);
            float v1 = w00*p1[r0*W_+c0] + w01*p1[r0*W_+c1] + w10*p1[r1*W_+c0] + w11*p1[r1*W_+c1];
            float v2 = w00*p2[r0*W_+c0] + w01*p2[r0*W_+c1] + w10*p2[r1*W_+c0] + w11*p2[r1*W_+c1];
            cbf[r*44 + cq*4 + i] = (1.0f - cfv)*v1 + cfv*v2;
          }
        }
      }
    }
  }
  __syncthreads();

  // ---- stage 2: dilate compute (results in regs; dilbuf will alias convbuf) ----
  float accA[4] = {-INFINITY, -INFINITY, -INFINITY, -INFINITY};
  float accB[4] = {-INFINITY, -INFINITY, -INFINITY, -INFINITY};
  switch (wid) {
    case 0: dil_compute<0>(smem, kdilL, lane, accA, accB); break;
    case 1: dil_compute<1>(smem, kdilL, lane, accA, accB); break;
    case 2: dil_compute<2>(smem, kdilL, lane, accA, accB); break;
    case 3: dil_compute<3>(smem, kdilL, lane, accA, accB); break;
    case 4: dil_compute<4>(smem, kdilL, lane, accA, accB); break;
    case 5: dil_compute<5>(smem, kdilL, lane, accA, accB); break;
    case 6: dil_compute<6>(smem, kdilL, lane, accA, accB); break;
    default: dil_compute<7>(smem, kdilL, lane, accA, accB); break;
  }
  __syncthreads();   // all conv reads complete; safe to overwrite

  // ---- stage 2a: write dilate results into aliased dilbuf ----
  {
    f4* db = smem + wid*DB_PL4;
    int rA = lane / 5, cA = lane - rA*5;
    f4 vA = {accA[0], accA[1], accA[2], accA[3]};
    db[rA*STR4 + cA] = vA;
    if (lane < 36) {
      int g = lane + 64;
      int rB = g / 5, cB = g - rB*5;
      f4 vB = {accB[0], accB[1], accB[2], accB[3]};
      db[rB*STR4 + cB] = vB;
    }
  }
  __syncthreads();

  // ---- stage 2b: replicate dilbuf halo for edge tiles (clamped semantics) ----
  if ((h0 == 0) | (h0 == 112) | (w0 == 0) | (w0 == 112)) {
    float* df = (float*)smem;
    #pragma unroll
    for (int k2 = 0; k2 < 7; ++k2) {
      int i = t + k2*512;
      if (i < 3200) {                    // 8 o x 20 x 20
        int o = i / 400, rest = i - o*400;
        int row = rest / 20, col = rest - row*20;
        int vh = h0 - 2 + row, vw = w0 - 2 + col;
        int dr = min(max(vh, 0), 127) - vh;
        int dc = min(max(vw, 0), 127) - vw;
        if ((dr | dc) != 0) {
          df[o*(DB_PL4*4) + row*44 + col] =
            df[o*(DB_PL4*4) + (row + dr)*44 + col + dc];
        }
      }
    }
  }
  __syncthreads();

  // ---- stage 3: erode -> u3 ----
  {
    float* dst = u3 + ((b*CIN + c)*OR_ + wid)*PLANE + h0*W_ + w0;
    switch (wid) {
      case 0: ero_compute<0>(smem, keroL, lane, dst); break;
      case 1: ero_compute<1>(smem, keroL, lane, dst); break;
      case 2: ero_compute<2>(smem, keroL, lane, dst); break;
      case 3: ero_compute<3>(smem, keroL, lane, dst); break;
      case 4: ero_compute<4>(smem, keroL, lane, dst); break;
      case 5: ero_compute<5>(smem, keroL, lane, dst); break;
      case 6: ero_compute<6>(smem, keroL, lane, dst); break;
      default: ero_compute<7>(smem, keroL, lane, dst); break;
    }
  }
}

__global__ void gram_kernel(const float* __restrict__ u, double* __restrict__ part) {
  int t8 = blockIdx.x*256 + threadIdx.x;     // NPOS/8 = 65536 threads
  int hw = (t8 & 2047) << 3;
  int o  = (t8 >> 11) & 7;
  int b  = t8 >> 14;
  const float* base = u + b*BATCH_STR + o*PLANE + hw;
  f4 v0[8], v1[8];
  #pragma unroll
  for (int c = 0; c < 8; c++) {
    v0[c] = *(const f4*)(base + c*CH_STR);
    v1[c] = *(const f4*)(base + c*CH_STR + 4);
  }
  float S[8], G[36];
  #pragma unroll
  for (int c = 0; c < 8; c++)
    S[c] = (v0[c].x + v0[c].y) + (v0[c].z + v0[c].w)
         + (v1[c].x + v1[c].y) + (v1[c].z + v1[c].w);
  {
    int t = 0;
    #pragma unroll
    for (int c = 0; c < 8; c++)
      #pragma unroll
      for (int c2 = c; c2 < 8; c2++) {
        G[t] = v0[c].x*v0[c2].x + v0[c].y*v0[c2].y + v0[c].z*v0[c2].z + v0[c].w*v0[c2].w
             + v1[c].x*v1[c2].x + v1[c].y*v1[c2].y + v1[c].z*v1[c2].z + v1[c].w*v1[c2].w;
        t++;
      }
  }
  __shared__ double lds[4][44];
  int lane = threadIdx.x & 63;
  int wave = threadIdx.x >> 6;
  for (int t = 0; t < 44; t++) {
    double vv = (double)((t < 8) ? S[t] : G[t-8]);
    for (int off = 32; off; off >>= 1) vv += __shfl_down(vv, off);
    if (lane == 0) lds[wave][t] = vv;
  }
  __syncthreads();
  if (threadIdx.x < 44) {
    part[blockIdx.x*44 + threadIdx.x] =
      lds[0][threadIdx.x] + lds[1][threadIdx.x] + lds[2][threadIdx.x] + lds[3][threadIdx.x];
  }
}

__global__ void stats_kernel(const double* __restrict__ part, const float* __restrict__ weight,
                             const float* __restrict__ gamma, const float* __restrict__ beta,
                             float* __restrict__ ss) {
  __shared__ double tot[44];
  int t = threadIdx.x;
  if (t < 352) {
    int cnt = t >> 3, j = t & 7;
    double s = 0.0;
    #pragma unroll 8
    for (int k = 0; k < 32; ++k) s += part[(j + (k << 3))*44 + cnt];
    s += __shfl_down(s, 4);
    s += __shfl_down(s, 2);
    s += __shfl_down(s, 1);
    if (j == 0) tot[cnt] = s;
  }
  __syncthreads();
  if (t < 16) {
    double m = 0.0;
    for (int c = 0; c < 8; c++) m += (double)weight[c*COUT + t] * tot[c];
    double e2 = 0.0;
    int idx = 8;
    for (int c = 0; c < 8; c++)
      for (int c2 = c; c2 < 8; c2++) {
        double wp = (double)weight[c*COUT + t] * (double)weight[c2*COUT + t];
        e2 += (c2 == c ? 1.0 : 2.0) * wp * tot[idx];
        idx++;
      }
    double N = (double)NPOS;
    m /= N; e2 /= N;
    double var = e2 - m*m;
    double inv = rsqrt(var + 1e-5);
    float sc = (float)(inv * (double)gamma[t]);
    ss[t]      = sc;
    ss[16 + t] = beta[t] - (float)m * sc;
  }
}

__global__ void final_kernel(const float* __restrict__ u, const float* __restrict__ weight,
                             const float* __restrict__ ss, float* __restrict__ out) {
  __shared__ float Wsh[8][16];
  __shared__ float scale[16], shift[16];
  int t = threadIdx.x;
  if (t < 128) Wsh[t >> 4][t & 15] = weight[t];
  if (t < 16) { scale[t] = ss[t]; shift[t] = ss[16 + t]; }
  __syncthreads();
  int t4 = blockIdx.x*256 + threadIdx.x;     // 131072 threads
  int hw = (t4 & 4095) << 2;
  int o  = (t4 >> 12) & 7;
  int b  = t4 >> 15;
  const float* base = u + b*BATCH_STR + o*PLANE + hw;
  f4 v[8];
  #pragma unroll
  for (int c = 0; c < 8; c++) v[c] = *(const f4*)(base + c*CH_STR);
  float* ob = out + b*(COUT*CH_STR) + o*PLANE + hw;
  #pragma unroll
  for (int d = 0; d < 16; d++) {
    f4 y = {0.f, 0.f, 0.f, 0.f};
    #pragma unroll
    for (int c = 0; c < 8; c++) {
      float wv = Wsh[c][d];
      y.x = fmaf(v[c].x, wv, y.x);
      y.y = fmaf(v[c].y, wv, y.y);
      y.z = fmaf(v[c].z, wv, y.z);
      y.w = fmaf(v[c].w, wv, y.w);
    }
    float sc = scale[d], sh = shift[d];
    f4 r = { fmaf(y.x, sc, sh), fmaf(y.y, sc, sh), fmaf(y.z, sc, sh), fmaf(y.w, sc, sh) };
    *(f4*)(ob + d*CH_STR) = r;
  }
}

extern "C" void kernel_launch(void* const* d_in, const int* in_sizes, int n_in,
                              void* d_out, int out_size, void* d_ws, size_t ws_size,
                              hipStream_t stream) {
  const float* x      = (const float*)d_in[0];
  const float* g0     = (const float*)d_in[1];
  const float* mdil   = (const float*)d_in[2];
  const float* mero   = (const float*)d_in[3];
  const float* weight = (const float*)d_in[4];
  const float* gamma  = (const float*)d_in[5];
  const float* beta   = (const float*)d_in[6];
  float* out = (float*)d_out;

  char* ws = (char*)d_ws;
  float*  ss   = (float*)(ws + 8*1024);               // 32 floats
  double* part = (double*)(ws + 16*1024);             // 256*44*8 = 90 KB
  float*  u3   = (float*)(ws + (size_t)1*1024*1024);  // linear, 16 MB

  fused_kernel<<<B*CIN*64, 512, 0, stream>>>(x, g0, mdil, mero, u3);
  gram_kernel<<<NB_RED, 256, 0, stream>>>(u3, part);
  stats_kernel<<<1, 384, 0, stream>>>(part, weight, gamma, beta, ss);
  final_kernel<<<NPOS/4/256, 256, 0, stream>>>(u3, weight, ss, out);
}